// Round 3
// baseline (438.384 us; speedup 1.0000x reference)
//
#include <hip/hip_runtime.h>

// Problem constants (match reference setup_inputs)
constexpr int CN0 = 1000000;   // x rows
constexpr int CN1 = 300000;    // stem conv output rows
constexpr int CN2 = 80000;     // pooled rows
constexpr int CN3 = 30000;     // downsampled rows
constexpr float BN_EPS = 1e-5f;

typedef __attribute__((ext_vector_type(8))) short bf16x8;
typedef __attribute__((ext_vector_type(4))) float f32x4;

__device__ __forceinline__ float2 bn_ab(float s, float q, float invn, float gamma, float beta) {
  float m = s * invn;
  float v = fmaf(q, invn, -m * m);
  float rstd = rsqrtf(v + BN_EPS);
  float a = gamma * rstd;
  float b = beta - m * a;
  return make_float2(a, b);
}

// round-to-nearest-even fp32 -> bf16
__device__ __forceinline__ unsigned short f2bf(float f) {
  unsigned u = __float_as_uint(f);
  u += 0x7FFFu + ((u >> 16) & 1u);
  return (unsigned short)(u >> 16);
}

__device__ __forceinline__ float bf2f(unsigned short u) {
  return __uint_as_float(((unsigned)u) << 16);
}

// ---------------------------------------------------------------------------
// Prep: x (f32 [1M][4]) -> xbf (bf16 [1M][4])
// ---------------------------------------------------------------------------
__global__ __launch_bounds__(256) void k_prep_x(
    const float* __restrict__ x, unsigned int* __restrict__ xbf) {
  int i = blockIdx.x * 256 + threadIdx.x;
  if (i >= CN0) return;
  float4 v = *(const float4*)(x + i * 4);
  uint2 p;
  p.x = (unsigned)f2bf(v.x) | ((unsigned)f2bf(v.y) << 16);
  p.y = (unsigned)f2bf(v.z) | ((unsigned)f2bf(v.w) << 16);
  *(uint2*)(xbf + i * 2) = p;
}

// ---------------------------------------------------------------------------
// Prep: W_stem [27][4][64] f32 -> Wt [64 d][128 k] bf16 (K padded 108->128)
// ---------------------------------------------------------------------------
__global__ __launch_bounds__(256) void k_prep_stem(
    const float* __restrict__ W, unsigned short* __restrict__ Wt) {
  int e = blockIdx.x * 256 + threadIdx.x;  // 64*128 = 8192
  if (e >= 8192) return;
  int d = e >> 7, k = e & 127;
  Wt[e] = (k < 108) ? f2bf(W[k * 64 + d]) : (unsigned short)0;
}

// ---------------------------------------------------------------------------
// Weight prep: Wblk[k][d][cin] (bf16) from W[k][cin][d] (f32).
// Dual variant concatenates W1 (d 0..63) and Wd (d 64..127).
// ---------------------------------------------------------------------------
__global__ __launch_bounds__(256) void k_prep_dual(
    const float* __restrict__ W1, const float* __restrict__ Wd,
    unsigned short* __restrict__ Wdual) {
  int e = blockIdx.x * 256 + threadIdx.x;  // 27*128*64 = 221184
  if (e >= 27 * 128 * 64) return;
  int cin = e & 63, d = (e >> 6) & 127, k = e >> 13;
  float v = (d < 64) ? W1[(k * 64 + cin) * 64 + d]
                     : Wd[(k * 64 + cin) * 64 + (d - 64)];
  Wdual[e] = f2bf(v);
}

__global__ __launch_bounds__(256) void k_prep_res(
    const float* __restrict__ W2, unsigned short* __restrict__ Wres) {
  int e = blockIdx.x * 256 + threadIdx.x;  // 27*64*64 = 110592
  if (e >= 27 * 64 * 64) return;
  int cin = e & 63, d = (e >> 6) & 63, k = e >> 12;
  Wres[e] = f2bf(W2[(k * 64 + cin) * 64 + d]);
}

// ---------------------------------------------------------------------------
// Stem conv via MFMA: y1[N1][64](bf16) = gather(xbf, neigh) @ Wt.
// K = 27 taps x 4 cin = 108, padded to 128. Block: 64 nodes x 64 outs,
// 4 waves 2x2, wave tile 32x32, mfma_f32_16x16x32_bf16. XOR-swizzled LDS.
// Per-channel sum/sumsq into stats[0..63]/[64..127] (f32 from acc).
// ---------------------------------------------------------------------------
__global__ __launch_bounds__(256) void k_stem_mfma(
    const unsigned short* __restrict__ xbf, const int* __restrict__ neigh,
    const unsigned short* __restrict__ Wt, unsigned short* __restrict__ y1,
    float* __restrict__ stats) {
  __shared__ __align__(16) unsigned char Ab[64 * 256];  // 16 KB
  __shared__ __align__(16) unsigned char Bb[64 * 256];  // 16 KB
  const int tid = threadIdx.x;
  const int n0 = blockIdx.x * 64;
  const int lane = tid & 63;
  const int w = tid >> 6;
  const int wm = w >> 1, wn = w & 1;

  // Stage B (whole kernel's weights, once): 1024 uint4, swizzled
  {
    const uint4* Ws = (const uint4*)Wt;
#pragma unroll
    for (int j = 0; j < 4; ++j) {
      int p = tid + j * 256;
      int d = p >> 4, slot = p & 15;
      *(uint4*)(Bb + d * 256 + ((slot * 16) ^ ((d & 7) << 4))) = Ws[p];
    }
  }
  // Stage A: 64 nodes x 32 tap-slots (8B each; taps 27..31 & OOB rows -> 0)
#pragma unroll
  for (int j = 0; j < 8; ++j) {
    int e = tid + j * 256;
    int node = e >> 5, tap = e & 31;
    int row = n0 + node;
    uint2 v = {0u, 0u};
    if (row < CN1 && tap < 27) {
      int idx = neigh[row * 27 + tap];
      v = *(const uint2*)(xbf + idx * 4);
    }
    *(uint2*)(Ab + node * 256 + (((tap >> 1) * 16) ^ ((node & 7) << 4)) +
              (tap & 1) * 8) = v;
  }
  __syncthreads();

  f32x4 acc[2][2] = {};
#pragma unroll
  for (int ks = 0; ks < 4; ++ks) {
    int kb = ks * 64 + (lane >> 4) * 16;
    bf16x8 a[2], b[2];
#pragma unroll
    for (int mf = 0; mf < 2; ++mf) {
      int r = wm * 32 + mf * 16 + (lane & 15);
      a[mf] = *(const bf16x8*)(Ab + r * 256 + (kb ^ ((r & 7) << 4)));
    }
#pragma unroll
    for (int nf = 0; nf < 2; ++nf) {
      int d = wn * 32 + nf * 16 + (lane & 15);
      b[nf] = *(const bf16x8*)(Bb + d * 256 + (kb ^ ((d & 7) << 4)));
    }
#pragma unroll
    for (int mf = 0; mf < 2; ++mf)
#pragma unroll
      for (int nf = 0; nf < 2; ++nf)
        acc[mf][nf] = __builtin_amdgcn_mfma_f32_16x16x32_bf16(
            a[mf], b[nf], acc[mf][nf], 0, 0, 0);
  }

  // Store y1 bf16. C/D layout: col=lane&15, row=(lane>>4)*4+reg.
#pragma unroll
  for (int mf = 0; mf < 2; ++mf) {
    int rbase = n0 + wm * 32 + mf * 16 + (lane >> 4) * 4;
#pragma unroll
    for (int nf = 0; nf < 2; ++nf) {
      int c = wn * 32 + nf * 16 + (lane & 15);
#pragma unroll
      for (int r = 0; r < 4; ++r) {
        int row = rbase + r;
        if (row < CN1) y1[row * 64 + c] = f2bf(acc[mf][nf][r]);
      }
    }
  }

  // Stats: per-channel sum/sumsq (invalid rows contributed zeros)
#pragma unroll
  for (int nf = 0; nf < 2; ++nf) {
    float s = 0.f, q = 0.f;
#pragma unroll
    for (int mf = 0; mf < 2; ++mf)
#pragma unroll
      for (int r = 0; r < 4; ++r) {
        float v = acc[mf][nf][r];
        s += v; q += v * v;
      }
    s += __shfl_xor(s, 16); s += __shfl_xor(s, 32);
    q += __shfl_xor(q, 16); q += __shfl_xor(q, 32);
    if (lane < 16) {
      int c = wn * 32 + nf * 16 + lane;
      atomicAdd(&stats[c], s);
      atomicAdd(&stats[64 + c], q);
    }
  }
}

// ---------------------------------------------------------------------------
// Pool: h2[n][c] = relu(max_j BN(y1[child[n][j]][c])) on bf16 y1, packed
// 2 channels per uint. 8 nodes per block (32 threads/node).
// ---------------------------------------------------------------------------
__global__ __launch_bounds__(256) void k_pool(
    const unsigned int* __restrict__ y1, const int* __restrict__ child,
    const float* __restrict__ stats, const float* __restrict__ gamma,
    const float* __restrict__ beta, unsigned int* __restrict__ h2) {
  const int tid = threadIdx.x;
  const int wd = tid & 31;  // word index = channel pair
  const int n = blockIdx.x * 8 + (tid >> 5);
  const int c0 = wd * 2, c1 = c0 + 1;
  float2 ab0 = bn_ab(stats[c0], stats[64 + c0], 1.0f / CN1, gamma[c0], beta[c0]);
  float2 ab1 = bn_ab(stats[c1], stats[64 + c1], 1.0f / CN1, gamma[c1], beta[c1]);
  float mx0 = -INFINITY, mn0 = INFINITY, mx1 = -INFINITY, mn1 = INFINITY;
  const int* crow = child + n * 8;
#pragma unroll
  for (int j = 0; j < 8; ++j) {
    unsigned v = y1[crow[j] * 32 + wd];
    float v0 = __uint_as_float(v << 16);
    float v1 = __uint_as_float(v & 0xFFFF0000u);
    mx0 = fmaxf(mx0, v0); mn0 = fminf(mn0, v0);
    mx1 = fmaxf(mx1, v1); mn1 = fminf(mn1, v1);
  }
  float t0 = (ab0.x > 0.f) ? fmaf(ab0.x, mx0, ab0.y) : fmaf(ab0.x, mn0, ab0.y);
  float t1 = (ab1.x > 0.f) ? fmaf(ab1.x, mx1, ab1.y) : fmaf(ab1.x, mn1, ab1.y);
  unsigned o = (unsigned)f2bf(fmaxf(t0, 0.f)) |
               ((unsigned)f2bf(fmaxf(t1, 0.f)) << 16);
  h2[n * 32 + wd] = o;
}

// ---------------------------------------------------------------------------
// MFMA gathered conv (unchanged from round 1, verified).
// ---------------------------------------------------------------------------
template <int OUTC>
__global__ __launch_bounds__(256) void k_mconv(
    const unsigned short* __restrict__ src, const int* __restrict__ neigh,
    const unsigned short* __restrict__ Wblk, float* __restrict__ out,
    float* __restrict__ stats, int M) {
  constexpr int NF = OUTC / 32;
  constexpr int PPT = (OUTC * 128 / 16) / 256;
  __shared__ __align__(16) unsigned char Ab[64 * 128];
  __shared__ __align__(16) unsigned char Bb[OUTC * 128];
  __shared__ int nlds[64 * 27];

  const int tid = threadIdx.x;
  const int n0 = blockIdx.x * 64;
  const int lane = tid & 63;
  const int w = tid >> 6;
  const int wm = w >> 1, wn = w & 1;
  const int gi = tid >> 2;
  const int gq = tid & 3;
  const int swA = (gi & 7) << 4;

  for (int e = tid; e < 64 * 27; e += 256) {
    int row = n0 + e / 27;
    nlds[e] = (row < M) ? neigh[row * 27 + e % 27] : -1;
  }

  f32x4 acc[2][NF] = {};
  uint4 rA0 = {}, rA1 = {};
  uint4 rB[PPT];

  __syncthreads();

  {
    int idx = nlds[gi * 27 + 0];
    if (idx >= 0) {
      const uint4* s = (const uint4*)(src + idx * 64 + gq * 16);
      rA0 = s[0]; rA1 = s[1];
    } else {
      rA0 = uint4{0, 0, 0, 0}; rA1 = uint4{0, 0, 0, 0};
    }
    const uint4* Bs = (const uint4*)(Wblk);
#pragma unroll
    for (int j = 0; j < PPT; ++j) rB[j] = Bs[tid * PPT + j];
  }

  for (int k = 0; k < 27; ++k) {
    *(uint4*)(Ab + gi * 128 + ((gq * 32) ^ swA)) = rA0;
    *(uint4*)(Ab + gi * 128 + ((gq * 32 + 16) ^ swA)) = rA1;
#pragma unroll
    for (int j = 0; j < PPT; ++j) {
      int p = tid * PPT + j;
      int d = p >> 3;
      int rb = (p & 7) * 16;
      *(uint4*)(Bb + d * 128 + (rb ^ ((d & 7) << 4))) = rB[j];
    }
    if (k < 26) {
      int idx = nlds[gi * 27 + k + 1];
      if (idx >= 0) {
        const uint4* s = (const uint4*)(src + idx * 64 + gq * 16);
        rA0 = s[0]; rA1 = s[1];
      } else {
        rA0 = uint4{0, 0, 0, 0}; rA1 = uint4{0, 0, 0, 0};
      }
      const uint4* Bs = (const uint4*)(Wblk + (k + 1) * OUTC * 64);
#pragma unroll
      for (int j = 0; j < PPT; ++j) rB[j] = Bs[tid * PPT + j];
    }
    __syncthreads();
#pragma unroll
    for (int ks = 0; ks < 2; ++ks) {
      int kb = ks * 64 + (lane >> 4) * 16;
      bf16x8 a[2];
#pragma unroll
      for (int mf = 0; mf < 2; ++mf) {
        int r = wm * 32 + mf * 16 + (lane & 15);
        a[mf] = *(const bf16x8*)(Ab + r * 128 + (kb ^ ((r & 7) << 4)));
      }
#pragma unroll
      for (int nf = 0; nf < NF; ++nf) {
        int d = wn * (OUTC / 2) + nf * 16 + (lane & 15);
        bf16x8 b = *(const bf16x8*)(Bb + d * 128 + (kb ^ ((d & 7) << 4)));
#pragma unroll
        for (int mf = 0; mf < 2; ++mf)
          acc[mf][nf] = __builtin_amdgcn_mfma_f32_16x16x32_bf16(
              a[mf], b, acc[mf][nf], 0, 0, 0);
      }
    }
    __syncthreads();
  }

#pragma unroll
  for (int mf = 0; mf < 2; ++mf) {
    int rbase = n0 + wm * 32 + mf * 16 + (lane >> 4) * 4;
#pragma unroll
    for (int nf = 0; nf < NF; ++nf) {
      int c = wn * (OUTC / 2) + nf * 16 + (lane & 15);
#pragma unroll
      for (int r = 0; r < 4; ++r) {
        int row = rbase + r;
        if (row < M) out[row * OUTC + c] = acc[mf][nf][r];
      }
    }
  }

#pragma unroll
  for (int nf = 0; nf < NF; ++nf) {
    float s = 0.f, q = 0.f;
#pragma unroll
    for (int mf = 0; mf < 2; ++mf)
#pragma unroll
      for (int r = 0; r < 4; ++r) {
        float v = acc[mf][nf][r];
        s += v; q += v * v;
      }
    s += __shfl_xor(s, 16); s += __shfl_xor(s, 32);
    q += __shfl_xor(q, 16); q += __shfl_xor(q, 32);
    if (lane < 16) {
      int c = wn * (OUTC / 2) + nf * 16 + lane;
      atomicAdd(&stats[c], s);
      atomicAdd(&stats[OUTC + c], q);
    }
  }
}

// ---------------------------------------------------------------------------
// BN+ReLU on y2d channels 0..63 -> out1 (bf16)
// ---------------------------------------------------------------------------
__global__ __launch_bounds__(256) void k_bnrelu(
    const float* __restrict__ y2d, const float* __restrict__ stats,
    const float* __restrict__ gamma, const float* __restrict__ beta,
    unsigned short* __restrict__ out1) {
  int e = blockIdx.x * 256 + threadIdx.x;
  int i = e >> 6, c = e & 63;
  float2 ab = bn_ab(stats[c], stats[128 + c], 1.0f / CN3, gamma[c], beta[c]);
  out1[e] = f2bf(fmaxf(fmaf(ab.x, y2d[i * 128 + c], ab.y), 0.f));
}

// ---------------------------------------------------------------------------
// Final: relu(BN2(y3) + BNd(y2d[:,64:128]))
// ---------------------------------------------------------------------------
__global__ __launch_bounds__(256) void k_final(
    const float* __restrict__ y3, const float* __restrict__ y2d,
    const float* __restrict__ stats2, const float* __restrict__ stats1d,
    const float* __restrict__ g2, const float* __restrict__ b2,
    const float* __restrict__ gd, const float* __restrict__ bd,
    float* __restrict__ dout) {
  int e = blockIdx.x * 256 + threadIdx.x;
  int i = e >> 6, c = e & 63;
  float2 ab2 = bn_ab(stats2[c], stats2[64 + c], 1.0f / CN3, g2[c], b2[c]);
  float2 abd =
      bn_ab(stats1d[64 + c], stats1d[192 + c], 1.0f / CN3, gd[c], bd[c]);
  float o = fmaf(ab2.x, y3[e], ab2.y) + fmaf(abd.x, y2d[i * 128 + 64 + c], abd.y);
  dout[e] = fmaxf(o, 0.f);
}

// ---------------------------------------------------------------------------
extern "C" void kernel_launch(void* const* d_in, const int* in_sizes, int n_in,
                              void* d_out, int out_size, void* d_ws,
                              size_t ws_size, hipStream_t stream) {
  const float* x = (const float*)d_in[0];
  const int* neigh_stem = (const int*)d_in[1];
  const int* pool_child = (const int*)d_in[2];
  const int* neigh_ds = (const int*)d_in[3];
  const int* neigh_res = (const int*)d_in[4];
  const float* W_stem = (const float*)d_in[5];
  const float* g_stem = (const float*)d_in[6];
  const float* b_stem = (const float*)d_in[7];
  const float* W1 = (const float*)d_in[8];
  const float* g1 = (const float*)d_in[9];
  const float* b1 = (const float*)d_in[10];
  const float* W2 = (const float*)d_in[11];
  const float* g2 = (const float*)d_in[12];
  const float* b2 = (const float*)d_in[13];
  const float* Wd = (const float*)d_in[14];
  const float* gd = (const float*)d_in[15];
  const float* bd = (const float*)d_in[16];
  float* out = (float*)d_out;
  float* ws = (float*)d_ws;

  // Workspace layout (float units):
  unsigned short* y1bf = (unsigned short*)ws;              // N1*64 bf16 (9.6M f)
  float* y2d = ws;                                         // N3*128 f32 (reuse)
  unsigned short* out1bf = (unsigned short*)(ws + 3840000);// N3*64 bf16
  float* y3 = ws + 4800000;                                // N3*64 f32
  unsigned short* h2bf = (unsigned short*)(ws + 9600000);  // N2*64 bf16 (2.56M f)
  unsigned int* xbf = (unsigned int*)(ws + 12160000);      // N0*4 bf16 (2M f)
  unsigned short* Wst = (unsigned short*)(ws + 14160000);  // 8192 bf16
  unsigned short* Wdual = (unsigned short*)(ws + 14164096);// 27*128*64 bf16
  unsigned short* Wres = (unsigned short*)(ws + 14274688); // 27*64*64 bf16
  float* stats = ws + 14329984;                            // 512 f32
  float* stats_stem = stats;                               // [128]
  float* stats_1d = stats + 128;                           // [256]
  float* stats_2 = stats + 384;                            // [128]

  hipMemsetAsync(stats, 0, 512 * sizeof(float), stream);

  k_prep_x<<<(CN0 + 255) / 256, 256, 0, stream>>>(x, xbf);
  k_prep_stem<<<(8192 + 255) / 256, 256, 0, stream>>>(W_stem, Wst);
  k_prep_dual<<<(27 * 128 * 64 + 255) / 256, 256, 0, stream>>>(W1, Wd, Wdual);
  k_prep_res<<<(27 * 64 * 64 + 255) / 256, 256, 0, stream>>>(W2, Wres);

  k_stem_mfma<<<(CN1 + 63) / 64, 256, 0, stream>>>(
      (const unsigned short*)xbf, neigh_stem, Wst, y1bf, stats_stem);
  k_pool<<<CN2 / 8, 256, 0, stream>>>((const unsigned int*)y1bf, pool_child,
                                      stats_stem, g_stem, b_stem,
                                      (unsigned int*)h2bf);
  k_mconv<128><<<(CN3 + 63) / 64, 256, 0, stream>>>(h2bf, neigh_ds, Wdual,
                                                    y2d, stats_1d, CN3);
  k_bnrelu<<<CN3 * 64 / 256, 256, 0, stream>>>(y2d, stats_1d, g1, b1, out1bf);
  k_mconv<64><<<(CN3 + 63) / 64, 256, 0, stream>>>(out1bf, neigh_res, Wres,
                                                   y3, stats_2, CN3);
  k_final<<<CN3 * 64 / 256, 256, 0, stream>>>(y3, y2d, stats_2, stats_1d, g2,
                                              b2, gd, bd, out);
}

// Round 4
// 426.372 us; speedup vs baseline: 1.0282x; 1.0282x over previous
//
#include <hip/hip_runtime.h>

// Problem constants (match reference setup_inputs)
constexpr int CN0 = 1000000;   // x rows
constexpr int CN1 = 300000;    // stem conv output rows
constexpr int CN2 = 80000;     // pooled rows
constexpr int CN3 = 30000;     // downsampled rows
constexpr float BN_EPS = 1e-5f;

typedef __attribute__((ext_vector_type(8))) short bf16x8;
typedef __attribute__((ext_vector_type(4))) float f32x4;

__device__ __forceinline__ float2 bn_ab(float s, float q, float invn, float gamma, float beta) {
  float m = s * invn;
  float v = fmaf(q, invn, -m * m);
  float rstd = rsqrtf(v + BN_EPS);
  float a = gamma * rstd;
  float b = beta - m * a;
  return make_float2(a, b);
}

// round-to-nearest-even fp32 -> bf16
__device__ __forceinline__ unsigned short f2bf(float f) {
  unsigned u = __float_as_uint(f);
  u += 0x7FFFu + ((u >> 16) & 1u);
  return (unsigned short)(u >> 16);
}

// ---------------------------------------------------------------------------
// Prep: x (f32 [1M][4]) -> xbf (bf16 [1M][4])
// ---------------------------------------------------------------------------
__global__ __launch_bounds__(256) void k_prep_x(
    const float* __restrict__ x, unsigned int* __restrict__ xbf) {
  int i = blockIdx.x * 256 + threadIdx.x;
  if (i >= CN0) return;
  float4 v = *(const float4*)(x + i * 4);
  uint2 p;
  p.x = (unsigned)f2bf(v.x) | ((unsigned)f2bf(v.y) << 16);
  p.y = (unsigned)f2bf(v.z) | ((unsigned)f2bf(v.w) << 16);
  *(uint2*)(xbf + i * 2) = p;
}

// ---------------------------------------------------------------------------
// Prep: W_stem [27][4][64] f32 -> Wt [64 d][128 k] bf16 (K padded 108->128)
// ---------------------------------------------------------------------------
__global__ __launch_bounds__(256) void k_prep_stem(
    const float* __restrict__ W, unsigned short* __restrict__ Wt) {
  int e = blockIdx.x * 256 + threadIdx.x;  // 64*128 = 8192
  if (e >= 8192) return;
  int d = e >> 7, k = e & 127;
  Wt[e] = (k < 108) ? f2bf(W[k * 64 + d]) : (unsigned short)0;
}

// ---------------------------------------------------------------------------
// Weight prep: Wblk[k][d][cin] (bf16) from W[k][cin][d] (f32).
// ---------------------------------------------------------------------------
__global__ __launch_bounds__(256) void k_prep_dual(
    const float* __restrict__ W1, const float* __restrict__ Wd,
    unsigned short* __restrict__ Wdual) {
  int e = blockIdx.x * 256 + threadIdx.x;  // 27*128*64 = 221184
  if (e >= 27 * 128 * 64) return;
  int cin = e & 63, d = (e >> 6) & 127, k = e >> 13;
  float v = (d < 64) ? W1[(k * 64 + cin) * 64 + d]
                     : Wd[(k * 64 + cin) * 64 + (d - 64)];
  Wdual[e] = f2bf(v);
}

__global__ __launch_bounds__(256) void k_prep_res(
    const float* __restrict__ W2, unsigned short* __restrict__ Wres) {
  int e = blockIdx.x * 256 + threadIdx.x;  // 27*64*64 = 110592
  if (e >= 27 * 64 * 64) return;
  int cin = e & 63, d = (e >> 6) & 63, k = e >> 12;
  Wres[e] = f2bf(W2[(k * 64 + cin) * 64 + d]);
}

// ---------------------------------------------------------------------------
// Stem conv via MFMA. Staging is 3-phase (T14): (1) 8 independent neigh
// index loads -> regs, (2) 8 independent xbf gathers -> regs, (3) LDS writes.
// This keeps ~8 gathers in flight per thread instead of ~2 per wave.
// ---------------------------------------------------------------------------
__global__ __launch_bounds__(256) void k_stem_mfma(
    const unsigned short* __restrict__ xbf, const int* __restrict__ neigh,
    const unsigned short* __restrict__ Wt, unsigned short* __restrict__ y1,
    float* __restrict__ stats) {
  __shared__ __align__(16) unsigned char Ab[64 * 256];  // 16 KB
  __shared__ __align__(16) unsigned char Bb[64 * 256];  // 16 KB
  const int tid = threadIdx.x;
  const int n0 = blockIdx.x * 64;
  const int lane = tid & 63;
  const int w = tid >> 6;
  const int wm = w >> 1, wn = w & 1;

  // Phase 1: all 8 neighbor indices (independent loads)
  int idxs[8];
#pragma unroll
  for (int j = 0; j < 8; ++j) {
    int e = tid + j * 256;
    int node = e >> 5, tap = e & 31;
    int row = n0 + node;
    idxs[j] = (row < CN1 && tap < 27) ? neigh[row * 27 + tap] : -1;
  }
  // Phase 2: all 8 gathers (independent loads, 8 outstanding)
  uint2 vals[8];
#pragma unroll
  for (int j = 0; j < 8; ++j) {
    uint2 v = {0u, 0u};
    if (idxs[j] >= 0) v = *(const uint2*)(xbf + idxs[j] * 4);
    vals[j] = v;
  }
  // Stage B (whole kernel's weights): 1024 uint4, swizzled
  {
    const uint4* Ws = (const uint4*)Wt;
#pragma unroll
    for (int j = 0; j < 4; ++j) {
      int p = tid + j * 256;
      int d = p >> 4, slot = p & 15;
      *(uint4*)(Bb + d * 256 + ((slot * 16) ^ ((d & 7) << 4))) = Ws[p];
    }
  }
  // Phase 3: write staged A to LDS (swizzled)
#pragma unroll
  for (int j = 0; j < 8; ++j) {
    int e = tid + j * 256;
    int node = e >> 5, tap = e & 31;
    *(uint2*)(Ab + node * 256 + (((tap >> 1) * 16) ^ ((node & 7) << 4)) +
              (tap & 1) * 8) = vals[j];
  }
  __syncthreads();

  f32x4 acc[2][2] = {};
#pragma unroll
  for (int ks = 0; ks < 4; ++ks) {
    int kb = ks * 64 + (lane >> 4) * 16;
    bf16x8 a[2], b[2];
#pragma unroll
    for (int mf = 0; mf < 2; ++mf) {
      int r = wm * 32 + mf * 16 + (lane & 15);
      a[mf] = *(const bf16x8*)(Ab + r * 256 + (kb ^ ((r & 7) << 4)));
    }
#pragma unroll
    for (int nf = 0; nf < 2; ++nf) {
      int d = wn * 32 + nf * 16 + (lane & 15);
      b[nf] = *(const bf16x8*)(Bb + d * 256 + (kb ^ ((d & 7) << 4)));
    }
#pragma unroll
    for (int mf = 0; mf < 2; ++mf)
#pragma unroll
      for (int nf = 0; nf < 2; ++nf)
        acc[mf][nf] = __builtin_amdgcn_mfma_f32_16x16x32_bf16(
            a[mf], b[nf], acc[mf][nf], 0, 0, 0);
  }

  // Store y1 bf16. C/D layout: col=lane&15, row=(lane>>4)*4+reg.
#pragma unroll
  for (int mf = 0; mf < 2; ++mf) {
    int rbase = n0 + wm * 32 + mf * 16 + (lane >> 4) * 4;
#pragma unroll
    for (int nf = 0; nf < 2; ++nf) {
      int c = wn * 32 + nf * 16 + (lane & 15);
#pragma unroll
      for (int r = 0; r < 4; ++r) {
        int row = rbase + r;
        if (row < CN1) y1[row * 64 + c] = f2bf(acc[mf][nf][r]);
      }
    }
  }

  // Stats: per-channel sum/sumsq (invalid rows contributed zeros)
#pragma unroll
  for (int nf = 0; nf < 2; ++nf) {
    float s = 0.f, q = 0.f;
#pragma unroll
    for (int mf = 0; mf < 2; ++mf)
#pragma unroll
      for (int r = 0; r < 4; ++r) {
        float v = acc[mf][nf][r];
        s += v; q += v * v;
      }
    s += __shfl_xor(s, 16); s += __shfl_xor(s, 32);
    q += __shfl_xor(q, 16); q += __shfl_xor(q, 32);
    if (lane < 16) {
      int c = wn * 32 + nf * 16 + lane;
      atomicAdd(&stats[c], s);
      atomicAdd(&stats[64 + c], q);
    }
  }
}

// ---------------------------------------------------------------------------
// Pool: h2[n][c] = relu(max_j BN(y1[child[n][j]][c])) on packed bf16 y1.
// 3-phase: indices -> 8 independent row reads -> compute.
// ---------------------------------------------------------------------------
__global__ __launch_bounds__(256) void k_pool(
    const unsigned int* __restrict__ y1, const int* __restrict__ child,
    const float* __restrict__ stats, const float* __restrict__ gamma,
    const float* __restrict__ beta, unsigned int* __restrict__ h2) {
  const int tid = threadIdx.x;
  const int wd = tid & 31;  // word index = channel pair
  const int n = blockIdx.x * 8 + (tid >> 5);
  const int c0 = wd * 2, c1 = c0 + 1;
  const int* crow = child + n * 8;
  int ch[8];
#pragma unroll
  for (int j = 0; j < 8; ++j) ch[j] = crow[j];
  unsigned vv[8];
#pragma unroll
  for (int j = 0; j < 8; ++j) vv[j] = y1[ch[j] * 32 + wd];

  float2 ab0 = bn_ab(stats[c0], stats[64 + c0], 1.0f / CN1, gamma[c0], beta[c0]);
  float2 ab1 = bn_ab(stats[c1], stats[64 + c1], 1.0f / CN1, gamma[c1], beta[c1]);
  float mx0 = -INFINITY, mn0 = INFINITY, mx1 = -INFINITY, mn1 = INFINITY;
#pragma unroll
  for (int j = 0; j < 8; ++j) {
    float v0 = __uint_as_float(vv[j] << 16);
    float v1 = __uint_as_float(vv[j] & 0xFFFF0000u);
    mx0 = fmaxf(mx0, v0); mn0 = fminf(mn0, v0);
    mx1 = fmaxf(mx1, v1); mn1 = fminf(mn1, v1);
  }
  float t0 = (ab0.x > 0.f) ? fmaf(ab0.x, mx0, ab0.y) : fmaf(ab0.x, mn0, ab0.y);
  float t1 = (ab1.x > 0.f) ? fmaf(ab1.x, mx1, ab1.y) : fmaf(ab1.x, mn1, ab1.y);
  unsigned o = (unsigned)f2bf(fmaxf(t0, 0.f)) |
               ((unsigned)f2bf(fmaxf(t1, 0.f)) << 16);
  h2[n * 32 + wd] = o;
}

// ---------------------------------------------------------------------------
// MFMA gathered conv (unchanged, verified).
// ---------------------------------------------------------------------------
template <int OUTC>
__global__ __launch_bounds__(256) void k_mconv(
    const unsigned short* __restrict__ src, const int* __restrict__ neigh,
    const unsigned short* __restrict__ Wblk, float* __restrict__ out,
    float* __restrict__ stats, int M) {
  constexpr int NF = OUTC / 32;
  constexpr int PPT = (OUTC * 128 / 16) / 256;
  __shared__ __align__(16) unsigned char Ab[64 * 128];
  __shared__ __align__(16) unsigned char Bb[OUTC * 128];
  __shared__ int nlds[64 * 27];

  const int tid = threadIdx.x;
  const int n0 = blockIdx.x * 64;
  const int lane = tid & 63;
  const int w = tid >> 6;
  const int wm = w >> 1, wn = w & 1;
  const int gi = tid >> 2;
  const int gq = tid & 3;
  const int swA = (gi & 7) << 4;

  for (int e = tid; e < 64 * 27; e += 256) {
    int row = n0 + e / 27;
    nlds[e] = (row < M) ? neigh[row * 27 + e % 27] : -1;
  }

  f32x4 acc[2][NF] = {};
  uint4 rA0 = {}, rA1 = {};
  uint4 rB[PPT];

  __syncthreads();

  {
    int idx = nlds[gi * 27 + 0];
    if (idx >= 0) {
      const uint4* s = (const uint4*)(src + idx * 64 + gq * 16);
      rA0 = s[0]; rA1 = s[1];
    } else {
      rA0 = uint4{0, 0, 0, 0}; rA1 = uint4{0, 0, 0, 0};
    }
    const uint4* Bs = (const uint4*)(Wblk);
#pragma unroll
    for (int j = 0; j < PPT; ++j) rB[j] = Bs[tid * PPT + j];
  }

  for (int k = 0; k < 27; ++k) {
    *(uint4*)(Ab + gi * 128 + ((gq * 32) ^ swA)) = rA0;
    *(uint4*)(Ab + gi * 128 + ((gq * 32 + 16) ^ swA)) = rA1;
#pragma unroll
    for (int j = 0; j < PPT; ++j) {
      int p = tid * PPT + j;
      int d = p >> 3;
      int rb = (p & 7) * 16;
      *(uint4*)(Bb + d * 128 + (rb ^ ((d & 7) << 4))) = rB[j];
    }
    if (k < 26) {
      int idx = nlds[gi * 27 + k + 1];
      if (idx >= 0) {
        const uint4* s = (const uint4*)(src + idx * 64 + gq * 16);
        rA0 = s[0]; rA1 = s[1];
      } else {
        rA0 = uint4{0, 0, 0, 0}; rA1 = uint4{0, 0, 0, 0};
      }
      const uint4* Bs = (const uint4*)(Wblk + (k + 1) * OUTC * 64);
#pragma unroll
      for (int j = 0; j < PPT; ++j) rB[j] = Bs[tid * PPT + j];
    }
    __syncthreads();
#pragma unroll
    for (int ks = 0; ks < 2; ++ks) {
      int kb = ks * 64 + (lane >> 4) * 16;
      bf16x8 a[2];
#pragma unroll
      for (int mf = 0; mf < 2; ++mf) {
        int r = wm * 32 + mf * 16 + (lane & 15);
        a[mf] = *(const bf16x8*)(Ab + r * 128 + (kb ^ ((r & 7) << 4)));
      }
#pragma unroll
      for (int nf = 0; nf < NF; ++nf) {
        int d = wn * (OUTC / 2) + nf * 16 + (lane & 15);
        bf16x8 b = *(const bf16x8*)(Bb + d * 128 + (kb ^ ((d & 7) << 4)));
#pragma unroll
        for (int mf = 0; mf < 2; ++mf)
          acc[mf][nf] = __builtin_amdgcn_mfma_f32_16x16x32_bf16(
              a[mf], b, acc[mf][nf], 0, 0, 0);
      }
    }
    __syncthreads();
  }

#pragma unroll
  for (int mf = 0; mf < 2; ++mf) {
    int rbase = n0 + wm * 32 + mf * 16 + (lane >> 4) * 4;
#pragma unroll
    for (int nf = 0; nf < NF; ++nf) {
      int c = wn * (OUTC / 2) + nf * 16 + (lane & 15);
#pragma unroll
      for (int r = 0; r < 4; ++r) {
        int row = rbase + r;
        if (row < M) out[row * OUTC + c] = acc[mf][nf][r];
      }
    }
  }

#pragma unroll
  for (int nf = 0; nf < NF; ++nf) {
    float s = 0.f, q = 0.f;
#pragma unroll
    for (int mf = 0; mf < 2; ++mf)
#pragma unroll
      for (int r = 0; r < 4; ++r) {
        float v = acc[mf][nf][r];
        s += v; q += v * v;
      }
    s += __shfl_xor(s, 16); s += __shfl_xor(s, 32);
    q += __shfl_xor(q, 16); q += __shfl_xor(q, 32);
    if (lane < 16) {
      int c = wn * (OUTC / 2) + nf * 16 + lane;
      atomicAdd(&stats[c], s);
      atomicAdd(&stats[OUTC + c], q);
    }
  }
}

// ---------------------------------------------------------------------------
// BN+ReLU on y2d channels 0..63 -> out1 (bf16)
// ---------------------------------------------------------------------------
__global__ __launch_bounds__(256) void k_bnrelu(
    const float* __restrict__ y2d, const float* __restrict__ stats,
    const float* __restrict__ gamma, const float* __restrict__ beta,
    unsigned short* __restrict__ out1) {
  int e = blockIdx.x * 256 + threadIdx.x;
  int i = e >> 6, c = e & 63;
  float2 ab = bn_ab(stats[c], stats[128 + c], 1.0f / CN3, gamma[c], beta[c]);
  out1[e] = f2bf(fmaxf(fmaf(ab.x, y2d[i * 128 + c], ab.y), 0.f));
}

// ---------------------------------------------------------------------------
// Final: relu(BN2(y3) + BNd(y2d[:,64:128]))
// ---------------------------------------------------------------------------
__global__ __launch_bounds__(256) void k_final(
    const float* __restrict__ y3, const float* __restrict__ y2d,
    const float* __restrict__ stats2, const float* __restrict__ stats1d,
    const float* __restrict__ g2, const float* __restrict__ b2,
    const float* __restrict__ gd, const float* __restrict__ bd,
    float* __restrict__ dout) {
  int e = blockIdx.x * 256 + threadIdx.x;
  int i = e >> 6, c = e & 63;
  float2 ab2 = bn_ab(stats2[c], stats2[64 + c], 1.0f / CN3, g2[c], b2[c]);
  float2 abd =
      bn_ab(stats1d[64 + c], stats1d[192 + c], 1.0f / CN3, gd[c], bd[c]);
  float o = fmaf(ab2.x, y3[e], ab2.y) + fmaf(abd.x, y2d[i * 128 + 64 + c], abd.y);
  dout[e] = fmaxf(o, 0.f);
}

// ---------------------------------------------------------------------------
extern "C" void kernel_launch(void* const* d_in, const int* in_sizes, int n_in,
                              void* d_out, int out_size, void* d_ws,
                              size_t ws_size, hipStream_t stream) {
  const float* x = (const float*)d_in[0];
  const int* neigh_stem = (const int*)d_in[1];
  const int* pool_child = (const int*)d_in[2];
  const int* neigh_ds = (const int*)d_in[3];
  const int* neigh_res = (const int*)d_in[4];
  const float* W_stem = (const float*)d_in[5];
  const float* g_stem = (const float*)d_in[6];
  const float* b_stem = (const float*)d_in[7];
  const float* W1 = (const float*)d_in[8];
  const float* g1 = (const float*)d_in[9];
  const float* b1 = (const float*)d_in[10];
  const float* W2 = (const float*)d_in[11];
  const float* g2 = (const float*)d_in[12];
  const float* b2 = (const float*)d_in[13];
  const float* Wd = (const float*)d_in[14];
  const float* gd = (const float*)d_in[15];
  const float* bd = (const float*)d_in[16];
  float* out = (float*)d_out;
  float* ws = (float*)d_ws;

  // Workspace layout (float units):
  unsigned short* y1bf = (unsigned short*)ws;              // N1*64 bf16 (9.6M f)
  float* y2d = ws;                                         // N3*128 f32 (reuse)
  unsigned short* out1bf = (unsigned short*)(ws + 3840000);// N3*64 bf16
  float* y3 = ws + 4800000;                                // N3*64 f32
  unsigned short* h2bf = (unsigned short*)(ws + 9600000);  // N2*64 bf16 (2.56M f)
  unsigned int* xbf = (unsigned int*)(ws + 12160000);      // N0*4 bf16 (2M f)
  unsigned short* Wst = (unsigned short*)(ws + 14160000);  // 8192 bf16
  unsigned short* Wdual = (unsigned short*)(ws + 14164096);// 27*128*64 bf16
  unsigned short* Wres = (unsigned short*)(ws + 14274688); // 27*64*64 bf16
  float* stats = ws + 14329984;                            // 512 f32
  float* stats_stem = stats;                               // [128]
  float* stats_1d = stats + 128;                           // [256]
  float* stats_2 = stats + 384;                            // [128]

  hipMemsetAsync(stats, 0, 512 * sizeof(float), stream);

  k_prep_x<<<(CN0 + 255) / 256, 256, 0, stream>>>(x, xbf);
  k_prep_stem<<<(8192 + 255) / 256, 256, 0, stream>>>(W_stem, Wst);
  k_prep_dual<<<(27 * 128 * 64 + 255) / 256, 256, 0, stream>>>(W1, Wd, Wdual);
  k_prep_res<<<(27 * 64 * 64 + 255) / 256, 256, 0, stream>>>(W2, Wres);

  k_stem_mfma<<<(CN1 + 63) / 64, 256, 0, stream>>>(
      (const unsigned short*)xbf, neigh_stem, Wst, y1bf, stats_stem);
  k_pool<<<CN2 / 8, 256, 0, stream>>>((const unsigned int*)y1bf, pool_child,
                                      stats_stem, g_stem, b_stem,
                                      (unsigned int*)h2bf);
  k_mconv<128><<<(CN3 + 63) / 64, 256, 0, stream>>>(h2bf, neigh_ds, Wdual,
                                                    y2d, stats_1d, CN3);
  k_bnrelu<<<CN3 * 64 / 256, 256, 0, stream>>>(y2d, stats_1d, g1, b1, out1bf);
  k_mconv<64><<<(CN3 + 63) / 64, 256, 0, stream>>>(out1bf, neigh_res, Wres,
                                                   y3, stats_2, CN3);
  k_final<<<CN3 * 64 / 256, 256, 0, stream>>>(y3, y2d, stats_2, stats_1d, g2,
                                              b2, gd, bd, out);
}

// Round 5
// 290.861 us; speedup vs baseline: 1.5072x; 1.4659x over previous
//
#include <hip/hip_runtime.h>

// Problem constants (match reference setup_inputs)
constexpr int CN0 = 1000000;   // x rows
constexpr int CN1 = 300000;    // stem conv output rows
constexpr int CN2 = 80000;     // pooled rows
constexpr int CN3 = 30000;     // downsampled rows
constexpr float BN_EPS = 1e-5f;

typedef __attribute__((ext_vector_type(8))) short bf16x8;
typedef __attribute__((ext_vector_type(4))) float f32x4;

__device__ __forceinline__ float2 bn_ab(float s, float q, float invn, float gamma, float beta) {
  float m = s * invn;
  float v = fmaf(q, invn, -m * m);
  float rstd = rsqrtf(v + BN_EPS);
  float a = gamma * rstd;
  float b = beta - m * a;
  return make_float2(a, b);
}

// round-to-nearest-even fp32 -> bf16
__device__ __forceinline__ unsigned short f2bf(float f) {
  unsigned u = __float_as_uint(f);
  u += 0x7FFFu + ((u >> 16) & 1u);
  return (unsigned short)(u >> 16);
}

// LDS-only barrier: waits ds ops, does NOT drain vmcnt -> prefetched global
// loads stay in flight across the barrier (unlike __syncthreads lowering).
__device__ __forceinline__ void sync_lds() {
  asm volatile("s_waitcnt lgkmcnt(0)" ::: "memory");
  __builtin_amdgcn_s_barrier();
  asm volatile("" ::: "memory");
}

// ---------------------------------------------------------------------------
// Prep: x (f32 [1M][4]) -> xbf (bf16 [1M][4])
// ---------------------------------------------------------------------------
__global__ __launch_bounds__(256) void k_prep_x(
    const float* __restrict__ x, unsigned int* __restrict__ xbf) {
  int i = blockIdx.x * 256 + threadIdx.x;
  if (i >= CN0) return;
  float4 v = *(const float4*)(x + i * 4);
  uint2 p;
  p.x = (unsigned)f2bf(v.x) | ((unsigned)f2bf(v.y) << 16);
  p.y = (unsigned)f2bf(v.z) | ((unsigned)f2bf(v.w) << 16);
  *(uint2*)(xbf + i * 2) = p;
}

// ---------------------------------------------------------------------------
// Prep: W_stem [27][4][64] f32 -> Wt [64 d][128 k] bf16 (K padded 108->128)
// ---------------------------------------------------------------------------
__global__ __launch_bounds__(256) void k_prep_stem(
    const float* __restrict__ W, unsigned short* __restrict__ Wt) {
  int e = blockIdx.x * 256 + threadIdx.x;  // 64*128 = 8192
  if (e >= 8192) return;
  int d = e >> 7, k = e & 127;
  Wt[e] = (k < 108) ? f2bf(W[k * 64 + d]) : (unsigned short)0;
}

// ---------------------------------------------------------------------------
// Weight prep: Wblk[k][d][cin] (bf16) from W[k][cin][d] (f32).
// ---------------------------------------------------------------------------
__global__ __launch_bounds__(256) void k_prep_dual(
    const float* __restrict__ W1, const float* __restrict__ Wd,
    unsigned short* __restrict__ Wdual) {
  int e = blockIdx.x * 256 + threadIdx.x;  // 27*128*64 = 221184
  if (e >= 27 * 128 * 64) return;
  int cin = e & 63, d = (e >> 6) & 127, k = e >> 13;
  float v = (d < 64) ? W1[(k * 64 + cin) * 64 + d]
                     : Wd[(k * 64 + cin) * 64 + (d - 64)];
  Wdual[e] = f2bf(v);
}

__global__ __launch_bounds__(256) void k_prep_res(
    const float* __restrict__ W2, unsigned short* __restrict__ Wres) {
  int e = blockIdx.x * 256 + threadIdx.x;  // 27*64*64 = 110592
  if (e >= 27 * 64 * 64) return;
  int cin = e & 63, d = (e >> 6) & 63, k = e >> 12;
  Wres[e] = f2bf(W2[(k * 64 + cin) * 64 + d]);
}

// ---------------------------------------------------------------------------
// Stem conv via MFMA, pipelined over T tiles per block.
// Pipeline: idx loads 3 tiles ahead, gathers 1 tile ahead (regs), A double-
// buffered in LDS, B hoisted to registers once. lgkm-only barriers keep the
// next tile's gathers in flight across each barrier.
// ---------------------------------------------------------------------------
__global__ __launch_bounds__(256) void k_stem_mfma(
    const unsigned short* __restrict__ xbf, const int* __restrict__ neigh,
    const unsigned short* __restrict__ Wt, unsigned short* __restrict__ y1,
    float* __restrict__ stats) {
  constexpr int T = 4;  // tiles per block (4688 tiles = 4 * 1172 blocks)
  __shared__ __align__(16) unsigned char Ab[2][64 * 256];  // 2 x 16 KB
  __shared__ __align__(16) unsigned char Bb[64 * 256];     // 16 KB
  const int tid = threadIdx.x;
  const int lane = tid & 63;
  const int w = tid >> 6, wm = w >> 1, wn = w & 1;
  const int g0 = blockIdx.x * T;  // first tile index

  // B global loads first (oldest -> LDS-write waits only these)
  uint4 wreg[4];
  {
    const uint4* Ws = (const uint4*)Wt;
#pragma unroll
    for (int j = 0; j < 4; ++j) wreg[j] = Ws[tid + j * 256];
  }

  // idx loads: tile0 -> idx0; tile1 -> idxs[1]; tile2 -> idxs[0]
  int idx0[8], idxs[2][8];
  auto ldidx = [&](int t, int(&dst)[8]) {
#pragma unroll
    for (int j = 0; j < 8; ++j) {
      int e = tid + j * 256;
      int node = e >> 5, tap = e & 31;
      int row = (g0 + t) * 64 + node;
      dst[j] = (row < CN1 && tap < 27) ? neigh[row * 27 + tap] : -1;
    }
  };
  ldidx(0, idx0);
  ldidx(1, idxs[1]);
  ldidx(2, idxs[0]);

  // B -> LDS (swizzled); waits wreg only (idx loads stay in flight)
#pragma unroll
  for (int j = 0; j < 4; ++j) {
    int p = tid + j * 256;
    int d = p >> 4, slot = p & 15;
    *(uint4*)(Bb + d * 256 + ((slot * 16) ^ ((d & 7) << 4))) = wreg[j];
  }

  // gathers for tile 0 (waits idx0 only)
  uint2 vals[8];
#pragma unroll
  for (int j = 0; j < 8; ++j) {
    uint2 v = {0u, 0u};
    if (idx0[j] >= 0) v = *(const uint2*)(xbf + idx0[j] * 4);
    vals[j] = v;
  }

  sync_lds();  // Bb visible

  // hoist B fragments to registers (once per block)
  bf16x8 bfrag[4][2];
#pragma unroll
  for (int ks = 0; ks < 4; ++ks) {
    int kb = ks * 64 + (lane >> 4) * 16;
#pragma unroll
    for (int nf = 0; nf < 2; ++nf) {
      int d = wn * 32 + nf * 16 + (lane & 15);
      bfrag[ks][nf] = *(const bf16x8*)(Bb + d * 256 + (kb ^ ((d & 7) << 4)));
    }
  }

  float sacc[2] = {0.f, 0.f}, qacc[2] = {0.f, 0.f};

#pragma unroll
  for (int t = 0; t < T; ++t) {
    // (1) write gathered tile t to Ab[t&1] (waits tile-t gathers)
#pragma unroll
    for (int j = 0; j < 8; ++j) {
      int e = tid + j * 256;
      int node = e >> 5, tap = e & 31;
      *(uint2*)(Ab[t & 1] + node * 256 +
                (((tap >> 1) * 16) ^ ((node & 7) << 4)) + (tap & 1) * 8) =
          vals[j];
    }
    sync_lds();
    // (2) MFMA tile t
    f32x4 acc[2][2] = {};
#pragma unroll
    for (int ks = 0; ks < 4; ++ks) {
      int kb = ks * 64 + (lane >> 4) * 16;
      bf16x8 a[2];
#pragma unroll
      for (int mf = 0; mf < 2; ++mf) {
        int r = wm * 32 + mf * 16 + (lane & 15);
        a[mf] = *(const bf16x8*)(Ab[t & 1] + r * 256 + (kb ^ ((r & 7) << 4)));
      }
#pragma unroll
      for (int mf = 0; mf < 2; ++mf)
#pragma unroll
        for (int nf = 0; nf < 2; ++nf)
          acc[mf][nf] = __builtin_amdgcn_mfma_f32_16x16x32_bf16(
              a[mf], bfrag[ks][nf], acc[mf][nf], 0, 0, 0);
    }
    // (3) issue gathers for tile t+1 (ride latency across next barrier)
    if (t + 1 < T) {
#pragma unroll
      for (int j = 0; j < 8; ++j) {
        int id = idxs[(t + 1) & 1][j];
        uint2 v = {0u, 0u};
        if (id >= 0) v = *(const uint2*)(xbf + id * 4);
        vals[j] = v;
      }
    }
    // (4) load idx for tile t+3 into the slot just freed
    if (t + 3 < T) ldidx(t + 3, idxs[(t + 3) & 1]);
    // (5) epilogue: y1 stores + register stats
    int n0 = (g0 + t) * 64;
#pragma unroll
    for (int mf = 0; mf < 2; ++mf) {
      int rbase = n0 + wm * 32 + mf * 16 + (lane >> 4) * 4;
#pragma unroll
      for (int nf = 0; nf < 2; ++nf) {
        int c = wn * 32 + nf * 16 + (lane & 15);
#pragma unroll
        for (int r = 0; r < 4; ++r) {
          int row = rbase + r;
          float v = acc[mf][nf][r];
          if (row < CN1) y1[row * 64 + c] = f2bf(v);
          sacc[nf] += v;
          qacc[nf] = fmaf(v, v, qacc[nf]);
        }
      }
    }
  }

  // block-level stats reduce, one atomic set per block
#pragma unroll
  for (int nf = 0; nf < 2; ++nf) {
    float s = sacc[nf], q = qacc[nf];
    s += __shfl_xor(s, 16); s += __shfl_xor(s, 32);
    q += __shfl_xor(q, 16); q += __shfl_xor(q, 32);
    if (lane < 16) {
      int c = wn * 32 + nf * 16 + lane;
      atomicAdd(&stats[c], s);
      atomicAdd(&stats[64 + c], q);
    }
  }
}

// ---------------------------------------------------------------------------
// Pool: h2[n][c] = relu(max_j BN(y1[child[n][j]][c])) on packed bf16 y1.
// ---------------------------------------------------------------------------
__global__ __launch_bounds__(256) void k_pool(
    const unsigned int* __restrict__ y1, const int* __restrict__ child,
    const float* __restrict__ stats, const float* __restrict__ gamma,
    const float* __restrict__ beta, unsigned int* __restrict__ h2) {
  const int tid = threadIdx.x;
  const int wd = tid & 31;  // word index = channel pair
  const int n = blockIdx.x * 8 + (tid >> 5);
  const int c0 = wd * 2, c1 = c0 + 1;
  const int* crow = child + n * 8;
  int ch[8];
#pragma unroll
  for (int j = 0; j < 8; ++j) ch[j] = crow[j];
  unsigned vv[8];
#pragma unroll
  for (int j = 0; j < 8; ++j) vv[j] = y1[ch[j] * 32 + wd];

  float2 ab0 = bn_ab(stats[c0], stats[64 + c0], 1.0f / CN1, gamma[c0], beta[c0]);
  float2 ab1 = bn_ab(stats[c1], stats[64 + c1], 1.0f / CN1, gamma[c1], beta[c1]);
  float mx0 = -INFINITY, mn0 = INFINITY, mx1 = -INFINITY, mn1 = INFINITY;
#pragma unroll
  for (int j = 0; j < 8; ++j) {
    float v0 = __uint_as_float(vv[j] << 16);
    float v1 = __uint_as_float(vv[j] & 0xFFFF0000u);
    mx0 = fmaxf(mx0, v0); mn0 = fminf(mn0, v0);
    mx1 = fmaxf(mx1, v1); mn1 = fminf(mn1, v1);
  }
  float t0 = (ab0.x > 0.f) ? fmaf(ab0.x, mx0, ab0.y) : fmaf(ab0.x, mn0, ab0.y);
  float t1 = (ab1.x > 0.f) ? fmaf(ab1.x, mx1, ab1.y) : fmaf(ab1.x, mn1, ab1.y);
  unsigned o = (unsigned)f2bf(fmaxf(t0, 0.f)) |
               ((unsigned)f2bf(fmaxf(t1, 0.f)) << 16);
  h2[n * 32 + wd] = o;
}

// ---------------------------------------------------------------------------
// MFMA gathered conv. Same structure as before but lgkm-only barriers so the
// k+1 prefetch (rA/rB) stays in flight across both per-iter barriers.
// ---------------------------------------------------------------------------
template <int OUTC>
__global__ __launch_bounds__(256) void k_mconv(
    const unsigned short* __restrict__ src, const int* __restrict__ neigh,
    const unsigned short* __restrict__ Wblk, float* __restrict__ out,
    float* __restrict__ stats, int M) {
  constexpr int NF = OUTC / 32;
  constexpr int PPT = (OUTC * 128 / 16) / 256;
  __shared__ __align__(16) unsigned char Ab[64 * 128];
  __shared__ __align__(16) unsigned char Bb[OUTC * 128];
  __shared__ int nlds[64 * 27];

  const int tid = threadIdx.x;
  const int n0 = blockIdx.x * 64;
  const int lane = tid & 63;
  const int w = tid >> 6;
  const int wm = w >> 1, wn = w & 1;
  const int gi = tid >> 2;
  const int gq = tid & 3;
  const int swA = (gi & 7) << 4;

  for (int e = tid; e < 64 * 27; e += 256) {
    int row = n0 + e / 27;
    nlds[e] = (row < M) ? neigh[row * 27 + e % 27] : -1;
  }

  f32x4 acc[2][NF] = {};
  uint4 rA0 = {}, rA1 = {};
  uint4 rB[PPT];

  sync_lds();

  {
    int idx = nlds[gi * 27 + 0];
    if (idx >= 0) {
      const uint4* s = (const uint4*)(src + idx * 64 + gq * 16);
      rA0 = s[0]; rA1 = s[1];
    } else {
      rA0 = uint4{0, 0, 0, 0}; rA1 = uint4{0, 0, 0, 0};
    }
    const uint4* Bs = (const uint4*)(Wblk);
#pragma unroll
    for (int j = 0; j < PPT; ++j) rB[j] = Bs[tid * PPT + j];
  }

  for (int k = 0; k < 27; ++k) {
    *(uint4*)(Ab + gi * 128 + ((gq * 32) ^ swA)) = rA0;
    *(uint4*)(Ab + gi * 128 + ((gq * 32 + 16) ^ swA)) = rA1;
#pragma unroll
    for (int j = 0; j < PPT; ++j) {
      int p = tid * PPT + j;
      int d = p >> 3;
      int rb = (p & 7) * 16;
      *(uint4*)(Bb + d * 128 + (rb ^ ((d & 7) << 4))) = rB[j];
    }
    if (k < 26) {
      int idx = nlds[gi * 27 + k + 1];
      if (idx >= 0) {
        const uint4* s = (const uint4*)(src + idx * 64 + gq * 16);
        rA0 = s[0]; rA1 = s[1];
      } else {
        rA0 = uint4{0, 0, 0, 0}; rA1 = uint4{0, 0, 0, 0};
      }
      const uint4* Bs = (const uint4*)(Wblk + (k + 1) * OUTC * 64);
#pragma unroll
      for (int j = 0; j < PPT; ++j) rB[j] = Bs[tid * PPT + j];
    }
    sync_lds();
#pragma unroll
    for (int ks = 0; ks < 2; ++ks) {
      int kb = ks * 64 + (lane >> 4) * 16;
      bf16x8 a[2];
#pragma unroll
      for (int mf = 0; mf < 2; ++mf) {
        int r = wm * 32 + mf * 16 + (lane & 15);
        a[mf] = *(const bf16x8*)(Ab + r * 128 + (kb ^ ((r & 7) << 4)));
      }
#pragma unroll
      for (int nf = 0; nf < NF; ++nf) {
        int d = wn * (OUTC / 2) + nf * 16 + (lane & 15);
        bf16x8 b = *(const bf16x8*)(Bb + d * 128 + (kb ^ ((d & 7) << 4)));
#pragma unroll
        for (int mf = 0; mf < 2; ++mf)
          acc[mf][nf] = __builtin_amdgcn_mfma_f32_16x16x32_bf16(
              a[mf], b, acc[mf][nf], 0, 0, 0);
      }
    }
    sync_lds();
  }

#pragma unroll
  for (int mf = 0; mf < 2; ++mf) {
    int rbase = n0 + wm * 32 + mf * 16 + (lane >> 4) * 4;
#pragma unroll
    for (int nf = 0; nf < NF; ++nf) {
      int c = wn * (OUTC / 2) + nf * 16 + (lane & 15);
#pragma unroll
      for (int r = 0; r < 4; ++r) {
        int row = rbase + r;
        if (row < M) out[row * OUTC + c] = acc[mf][nf][r];
      }
    }
  }

#pragma unroll
  for (int nf = 0; nf < NF; ++nf) {
    float s = 0.f, q = 0.f;
#pragma unroll
    for (int mf = 0; mf < 2; ++mf)
#pragma unroll
      for (int r = 0; r < 4; ++r) {
        float v = acc[mf][nf][r];
        s += v; q += v * v;
      }
    s += __shfl_xor(s, 16); s += __shfl_xor(s, 32);
    q += __shfl_xor(q, 16); q += __shfl_xor(q, 32);
    if (lane < 16) {
      int c = wn * (OUTC / 2) + nf * 16 + lane;
      atomicAdd(&stats[c], s);
      atomicAdd(&stats[OUTC + c], q);
    }
  }
}

// ---------------------------------------------------------------------------
// BN+ReLU on y2d channels 0..63 -> out1 (bf16)
// ---------------------------------------------------------------------------
__global__ __launch_bounds__(256) void k_bnrelu(
    const float* __restrict__ y2d, const float* __restrict__ stats,
    const float* __restrict__ gamma, const float* __restrict__ beta,
    unsigned short* __restrict__ out1) {
  int e = blockIdx.x * 256 + threadIdx.x;
  int i = e >> 6, c = e & 63;
  float2 ab = bn_ab(stats[c], stats[128 + c], 1.0f / CN3, gamma[c], beta[c]);
  out1[e] = f2bf(fmaxf(fmaf(ab.x, y2d[i * 128 + c], ab.y), 0.f));
}

// ---------------------------------------------------------------------------
// Final: relu(BN2(y3) + BNd(y2d[:,64:128]))
// ---------------------------------------------------------------------------
__global__ __launch_bounds__(256) void k_final(
    const float* __restrict__ y3, const float* __restrict__ y2d,
    const float* __restrict__ stats2, const float* __restrict__ stats1d,
    const float* __restrict__ g2, const float* __restrict__ b2,
    const float* __restrict__ gd, const float* __restrict__ bd,
    float* __restrict__ dout) {
  int e = blockIdx.x * 256 + threadIdx.x;
  int i = e >> 6, c = e & 63;
  float2 ab2 = bn_ab(stats2[c], stats2[64 + c], 1.0f / CN3, g2[c], b2[c]);
  float2 abd =
      bn_ab(stats1d[64 + c], stats1d[192 + c], 1.0f / CN3, gd[c], bd[c]);
  float o = fmaf(ab2.x, y3[e], ab2.y) + fmaf(abd.x, y2d[i * 128 + 64 + c], abd.y);
  dout[e] = fmaxf(o, 0.f);
}

// ---------------------------------------------------------------------------
extern "C" void kernel_launch(void* const* d_in, const int* in_sizes, int n_in,
                              void* d_out, int out_size, void* d_ws,
                              size_t ws_size, hipStream_t stream) {
  const float* x = (const float*)d_in[0];
  const int* neigh_stem = (const int*)d_in[1];
  const int* pool_child = (const int*)d_in[2];
  const int* neigh_ds = (const int*)d_in[3];
  const int* neigh_res = (const int*)d_in[4];
  const float* W_stem = (const float*)d_in[5];
  const float* g_stem = (const float*)d_in[6];
  const float* b_stem = (const float*)d_in[7];
  const float* W1 = (const float*)d_in[8];
  const float* g1 = (const float*)d_in[9];
  const float* b1 = (const float*)d_in[10];
  const float* W2 = (const float*)d_in[11];
  const float* g2 = (const float*)d_in[12];
  const float* b2 = (const float*)d_in[13];
  const float* Wd = (const float*)d_in[14];
  const float* gd = (const float*)d_in[15];
  const float* bd = (const float*)d_in[16];
  float* out = (float*)d_out;
  float* ws = (float*)d_ws;

  // Workspace layout (float units):
  unsigned short* y1bf = (unsigned short*)ws;              // N1*64 bf16 (9.6M f)
  float* y2d = ws;                                         // N3*128 f32 (reuse)
  unsigned short* out1bf = (unsigned short*)(ws + 3840000);// N3*64 bf16
  float* y3 = ws + 4800000;                                // N3*64 f32
  unsigned short* h2bf = (unsigned short*)(ws + 9600000);  // N2*64 bf16 (2.56M f)
  unsigned int* xbf = (unsigned int*)(ws + 12160000);      // N0*4 bf16 (2M f)
  unsigned short* Wst = (unsigned short*)(ws + 14160000);  // 8192 bf16
  unsigned short* Wdual = (unsigned short*)(ws + 14164096);// 27*128*64 bf16
  unsigned short* Wres = (unsigned short*)(ws + 14274688); // 27*64*64 bf16
  float* stats = ws + 14329984;                            // 512 f32
  float* stats_stem = stats;                               // [128]
  float* stats_1d = stats + 128;                           // [256]
  float* stats_2 = stats + 384;                            // [128]

  hipMemsetAsync(stats, 0, 512 * sizeof(float), stream);

  k_prep_x<<<(CN0 + 255) / 256, 256, 0, stream>>>(x, xbf);
  k_prep_stem<<<(8192 + 255) / 256, 256, 0, stream>>>(W_stem, Wst);
  k_prep_dual<<<(27 * 128 * 64 + 255) / 256, 256, 0, stream>>>(W1, Wd, Wdual);
  k_prep_res<<<(27 * 64 * 64 + 255) / 256, 256, 0, stream>>>(W2, Wres);

  // 4688 tiles of 64 nodes = 4 tiles x 1172 blocks
  k_stem_mfma<<<1172, 256, 0, stream>>>(
      (const unsigned short*)xbf, neigh_stem, Wst, y1bf, stats_stem);
  k_pool<<<CN2 / 8, 256, 0, stream>>>((const unsigned int*)y1bf, pool_child,
                                      stats_stem, g_stem, b_stem,
                                      (unsigned int*)h2bf);
  k_mconv<128><<<(CN3 + 63) / 64, 256, 0, stream>>>(h2bf, neigh_ds, Wdual,
                                                    y2d, stats_1d, CN3);
  k_bnrelu<<<CN3 * 64 / 256, 256, 0, stream>>>(y2d, stats_1d, g1, b1, out1bf);
  k_mconv<64><<<(CN3 + 63) / 64, 256, 0, stream>>>(out1bf, neigh_res, Wres,
                                                   y3, stats_2, CN3);
  k_final<<<CN3 * 64 / 256, 256, 0, stream>>>(y3, y2d, stats_2, stats_1d, g2,
                                              b2, gd, bd, out);
}

// Round 6
// 277.467 us; speedup vs baseline: 1.5799x; 1.0483x over previous
//
#include <hip/hip_runtime.h>

// Problem constants (match reference setup_inputs)
constexpr int CN0 = 1000000;   // x rows
constexpr int CN1 = 300000;    // stem conv output rows
constexpr int CN2 = 80000;     // pooled rows
constexpr int CN3 = 30000;     // downsampled rows
constexpr float BN_EPS = 1e-5f;

typedef __attribute__((ext_vector_type(8))) short bf16x8;
typedef __attribute__((ext_vector_type(4))) float f32x4;

union FragU { uint4 u; bf16x8 b; };

__device__ __forceinline__ float2 bn_ab(float s, float q, float invn, float gamma, float beta) {
  float m = s * invn;
  float v = fmaf(q, invn, -m * m);
  float rstd = rsqrtf(v + BN_EPS);
  float a = gamma * rstd;
  float b = beta - m * a;
  return make_float2(a, b);
}

// round-to-nearest-even fp32 -> bf16
__device__ __forceinline__ unsigned short f2bf(float f) {
  unsigned u = __float_as_uint(f);
  u += 0x7FFFu + ((u >> 16) & 1u);
  return (unsigned short)(u >> 16);
}

// LDS-only barrier: waits ds ops, does NOT drain vmcnt -> prefetched global
// loads stay in flight across the barrier (unlike __syncthreads lowering).
__device__ __forceinline__ void sync_lds() {
  asm volatile("s_waitcnt lgkmcnt(0)" ::: "memory");
  __builtin_amdgcn_s_barrier();
  asm volatile("" ::: "memory");
}

// ---------------------------------------------------------------------------
// Prep: x (f32 [1M][4]) -> xbf (bf16 [1M][4])
// ---------------------------------------------------------------------------
__global__ __launch_bounds__(256) void k_prep_x(
    const float* __restrict__ x, unsigned int* __restrict__ xbf) {
  int i = blockIdx.x * 256 + threadIdx.x;
  if (i >= CN0) return;
  float4 v = *(const float4*)(x + i * 4);
  uint2 p;
  p.x = (unsigned)f2bf(v.x) | ((unsigned)f2bf(v.y) << 16);
  p.y = (unsigned)f2bf(v.z) | ((unsigned)f2bf(v.w) << 16);
  *(uint2*)(xbf + i * 2) = p;
}

// ---------------------------------------------------------------------------
// Prep: W_stem [27][4][64] f32 -> per-lane MFMA B fragments:
// Wf[((ks*4+nf)*64 + lane)*8 + e] = W[k][d], k = ks*32+(lane>>4)*8+e (0 pad
// for k>=108), d = nf*16+(lane&15).  (k flat = tap*4+cin)
// ---------------------------------------------------------------------------
__global__ __launch_bounds__(256) void k_prep_stem(
    const float* __restrict__ W, unsigned short* __restrict__ Wf) {
  int f = blockIdx.x * 256 + threadIdx.x;  // 8192
  if (f >= 8192) return;
  int e = f & 7, lane = (f >> 3) & 63, nf = (f >> 9) & 3, ks = f >> 11;
  int k = ks * 32 + (lane >> 4) * 8 + e;
  int d = nf * 16 + (lane & 15);
  Wf[f] = (k < 108) ? f2bf(W[k * 64 + d]) : (unsigned short)0;
}

// ---------------------------------------------------------------------------
// Weight prep: Wblk[k][d][cin] (bf16) from W[k][cin][d] (f32).
// ---------------------------------------------------------------------------
__global__ __launch_bounds__(256) void k_prep_dual(
    const float* __restrict__ W1, const float* __restrict__ Wd,
    unsigned short* __restrict__ Wdual) {
  int e = blockIdx.x * 256 + threadIdx.x;  // 27*128*64 = 221184
  if (e >= 27 * 128 * 64) return;
  int cin = e & 63, d = (e >> 6) & 127, k = e >> 13;
  float v = (d < 64) ? W1[(k * 64 + cin) * 64 + d]
                     : Wd[(k * 64 + cin) * 64 + (d - 64)];
  Wdual[e] = f2bf(v);
}

__global__ __launch_bounds__(256) void k_prep_res(
    const float* __restrict__ W2, unsigned short* __restrict__ Wres) {
  int e = blockIdx.x * 256 + threadIdx.x;  // 27*64*64 = 110592
  if (e >= 27 * 64 * 64) return;
  int cin = e & 63, d = (e >> 6) & 63, k = e >> 12;
  Wres[e] = f2bf(W2[(k * 64 + cin) * 64 + d]);
}

// ---------------------------------------------------------------------------
// Stem conv via MFMA, register-direct gather (no A-LDS, no per-tile
// barriers). Each wave owns 16 nodes x 64 cols per tile; a lane's A-fragment
// for sub-step ks is exactly two 8B gathers (taps 2t,2t+1 of its node).
// Pipeline: idx 2 tiles ahead, gathers 1 tile ahead, both ride out their
// latency under compute+store (compiler emits counted vmcnt).
// ---------------------------------------------------------------------------
__global__ __launch_bounds__(256) void k_stem_mfma(
    const unsigned short* __restrict__ xbf, const int* __restrict__ neigh,
    const unsigned short* __restrict__ Wf, unsigned short* __restrict__ y1,
    float* __restrict__ stats) {
  constexpr int T = 4;  // tiles (of 64 nodes) per block; 1172 blocks
  __shared__ __align__(16) uint4 Bb[1024];  // 16 KB: B fragments, staged once
  const int tid = threadIdx.x;
  const int lane = tid & 63;
  const int wv = tid >> 6;
  const int l15 = lane & 15, lq = lane >> 4;
  const int g0 = blockIdx.x * T;

  // Stage B fragments (linear copy, conflict-free reads later)
  {
    const uint4* Wsrc = (const uint4*)Wf;
#pragma unroll
    for (int j = 0; j < 4; ++j) Bb[tid + j * 256] = Wsrc[tid + j * 256];
  }
  __syncthreads();  // nothing valuable in flight yet

  int idxA[8], idxB[8];
  FragU fragA[4], fragB[4];

#define LDIDX(g, dst)                                                   \
  {                                                                     \
    int node_ = (g)*64 + wv * 16 + l15;                                 \
    bool rowok_ = node_ < CN1;                                          \
    const int* nb_ = neigh + node_ * 27;                                \
    _Pragma("unroll") for (int ks_ = 0; ks_ < 4; ++ks_) {               \
      int tap0_ = ks_ * 8 + lq * 2;                                     \
      dst[ks_ * 2] = (rowok_ && tap0_ < 27) ? nb_[tap0_] : -1;          \
      dst[ks_ * 2 + 1] = (rowok_ && tap0_ + 1 < 27) ? nb_[tap0_ + 1] : -1; \
    }                                                                   \
  }

#define GATHER(idx, frag)                                               \
  {                                                                     \
    _Pragma("unroll") for (int ks_ = 0; ks_ < 4; ++ks_) {               \
      uint2 v0_ = {0u, 0u}, v1_ = {0u, 0u};                             \
      if (idx[ks_ * 2] >= 0)                                            \
        v0_ = *(const uint2*)(xbf + idx[ks_ * 2] * 4);                  \
      if (idx[ks_ * 2 + 1] >= 0)                                        \
        v1_ = *(const uint2*)(xbf + idx[ks_ * 2 + 1] * 4);              \
      frag[ks_].u.x = v0_.x; frag[ks_].u.y = v0_.y;                     \
      frag[ks_].u.z = v1_.x; frag[ks_].u.w = v1_.y;                     \
    }                                                                   \
  }

  // prologue: tile0 idx -> tile0 gathers -> tile1 idx
  LDIDX(g0 + 0, idxA);
  GATHER(idxA, fragA);
  LDIDX(g0 + 1, idxB);

  float sacc[4] = {0.f, 0.f, 0.f, 0.f};
  float qacc[4] = {0.f, 0.f, 0.f, 0.f};

#pragma unroll
  for (int t = 0; t < T; ++t) {
    FragU* cur = (t & 1) ? fragB : fragA;
    FragU* nxt = (t & 1) ? fragA : fragB;
    int* idn = (t & 1) ? idxA : idxB;    // idx of tile t+1 (already loaded)
    int* idn2 = (t & 1) ? idxB : idxA;   // slot for idx of tile t+2
    // issue next tile's gathers + idx loads (ride latency under compute)
    if (t + 1 < T) GATHER(idn, nxt);
    if (t + 2 < T) LDIDX(g0 + t + 2, idn2);

    // compute: 4 K-substeps x 4 col-fragments; B from LDS
    f32x4 acc[4] = {};
#pragma unroll
    for (int ks = 0; ks < 4; ++ks) {
#pragma unroll
      for (int nf = 0; nf < 4; ++nf) {
        bf16x8 b = *(const bf16x8*)&Bb[(ks * 4 + nf) * 64 + lane];
        acc[nf] = __builtin_amdgcn_mfma_f32_16x16x32_bf16(cur[ks].b, b,
                                                          acc[nf], 0, 0, 0);
      }
    }

    // epilogue: store + register stats. C/D: col=lane&15, row=(lane>>4)*4+r
    int n0 = (g0 + t) * 64 + wv * 16;
#pragma unroll
    for (int nf = 0; nf < 4; ++nf) {
      int c = nf * 16 + l15;
#pragma unroll
      for (int r = 0; r < 4; ++r) {
        int row = n0 + lq * 4 + r;
        float v = acc[nf][r];
        if (row < CN1) y1[row * 64 + c] = f2bf(v);
        sacc[nf] += v;
        qacc[nf] = fmaf(v, v, qacc[nf]);
      }
    }
  }
#undef LDIDX
#undef GATHER

  // cross-wave stats reduction (reuse Bb as scratch), one atomic set/block
  __syncthreads();
  float* S = (float*)Bb;  // [2][4 waves][64 cols]
#pragma unroll
  for (int nf = 0; nf < 4; ++nf) {
    float s = sacc[nf], q = qacc[nf];
    s += __shfl_xor(s, 16); s += __shfl_xor(s, 32);
    q += __shfl_xor(q, 16); q += __shfl_xor(q, 32);
    if (lane < 16) {
      S[wv * 64 + nf * 16 + lane] = s;
      S[256 + wv * 64 + nf * 16 + lane] = q;
    }
  }
  __syncthreads();
  if (tid < 64) {
    float s = S[tid] + S[64 + tid] + S[128 + tid] + S[192 + tid];
    float q = S[256 + tid] + S[320 + tid] + S[384 + tid] + S[448 + tid];
    atomicAdd(&stats[tid], s);
    atomicAdd(&stats[64 + tid], q);
  }
}

// ---------------------------------------------------------------------------
// Pool: h2[n][c] = relu(max_j BN(y1[child[n][j]][c])) on packed bf16 y1.
// ---------------------------------------------------------------------------
__global__ __launch_bounds__(256) void k_pool(
    const unsigned int* __restrict__ y1, const int* __restrict__ child,
    const float* __restrict__ stats, const float* __restrict__ gamma,
    const float* __restrict__ beta, unsigned int* __restrict__ h2) {
  const int tid = threadIdx.x;
  const int wd = tid & 31;  // word index = channel pair
  const int n = blockIdx.x * 8 + (tid >> 5);
  const int c0 = wd * 2, c1 = c0 + 1;
  const int* crow = child + n * 8;
  int ch[8];
#pragma unroll
  for (int j = 0; j < 8; ++j) ch[j] = crow[j];
  unsigned vv[8];
#pragma unroll
  for (int j = 0; j < 8; ++j) vv[j] = y1[ch[j] * 32 + wd];

  float2 ab0 = bn_ab(stats[c0], stats[64 + c0], 1.0f / CN1, gamma[c0], beta[c0]);
  float2 ab1 = bn_ab(stats[c1], stats[64 + c1], 1.0f / CN1, gamma[c1], beta[c1]);
  float mx0 = -INFINITY, mn0 = INFINITY, mx1 = -INFINITY, mn1 = INFINITY;
#pragma unroll
  for (int j = 0; j < 8; ++j) {
    float v0 = __uint_as_float(vv[j] << 16);
    float v1 = __uint_as_float(vv[j] & 0xFFFF0000u);
    mx0 = fmaxf(mx0, v0); mn0 = fminf(mn0, v0);
    mx1 = fmaxf(mx1, v1); mn1 = fminf(mn1, v1);
  }
  float t0 = (ab0.x > 0.f) ? fmaf(ab0.x, mx0, ab0.y) : fmaf(ab0.x, mn0, ab0.y);
  float t1 = (ab1.x > 0.f) ? fmaf(ab1.x, mx1, ab1.y) : fmaf(ab1.x, mn1, ab1.y);
  unsigned o = (unsigned)f2bf(fmaxf(t0, 0.f)) |
               ((unsigned)f2bf(fmaxf(t1, 0.f)) << 16);
  h2[n * 32 + wd] = o;
}

// ---------------------------------------------------------------------------
// MFMA gathered conv. lgkm-only barriers keep the k+1 prefetch in flight.
// ---------------------------------------------------------------------------
template <int OUTC>
__global__ __launch_bounds__(256) void k_mconv(
    const unsigned short* __restrict__ src, const int* __restrict__ neigh,
    const unsigned short* __restrict__ Wblk, float* __restrict__ out,
    float* __restrict__ stats, int M) {
  constexpr int NF = OUTC / 32;
  constexpr int PPT = (OUTC * 128 / 16) / 256;
  __shared__ __align__(16) unsigned char Ab[64 * 128];
  __shared__ __align__(16) unsigned char Bb[OUTC * 128];
  __shared__ int nlds[64 * 27];

  const int tid = threadIdx.x;
  const int n0 = blockIdx.x * 64;
  const int lane = tid & 63;
  const int w = tid >> 6;
  const int wm = w >> 1, wn = w & 1;
  const int gi = tid >> 2;
  const int gq = tid & 3;
  const int swA = (gi & 7) << 4;

  for (int e = tid; e < 64 * 27; e += 256) {
    int row = n0 + e / 27;
    nlds[e] = (row < M) ? neigh[row * 27 + e % 27] : -1;
  }

  f32x4 acc[2][NF] = {};
  uint4 rA0 = {}, rA1 = {};
  uint4 rB[PPT];

  sync_lds();

  {
    int idx = nlds[gi * 27 + 0];
    if (idx >= 0) {
      const uint4* s = (const uint4*)(src + idx * 64 + gq * 16);
      rA0 = s[0]; rA1 = s[1];
    } else {
      rA0 = uint4{0, 0, 0, 0}; rA1 = uint4{0, 0, 0, 0};
    }
    const uint4* Bs = (const uint4*)(Wblk);
#pragma unroll
    for (int j = 0; j < PPT; ++j) rB[j] = Bs[tid * PPT + j];
  }

  for (int k = 0; k < 27; ++k) {
    *(uint4*)(Ab + gi * 128 + ((gq * 32) ^ swA)) = rA0;
    *(uint4*)(Ab + gi * 128 + ((gq * 32 + 16) ^ swA)) = rA1;
#pragma unroll
    for (int j = 0; j < PPT; ++j) {
      int p = tid * PPT + j;
      int d = p >> 3;
      int rb = (p & 7) * 16;
      *(uint4*)(Bb + d * 128 + (rb ^ ((d & 7) << 4))) = rB[j];
    }
    if (k < 26) {
      int idx = nlds[gi * 27 + k + 1];
      if (idx >= 0) {
        const uint4* s = (const uint4*)(src + idx * 64 + gq * 16);
        rA0 = s[0]; rA1 = s[1];
      } else {
        rA0 = uint4{0, 0, 0, 0}; rA1 = uint4{0, 0, 0, 0};
      }
      const uint4* Bs = (const uint4*)(Wblk + (k + 1) * OUTC * 64);
#pragma unroll
      for (int j = 0; j < PPT; ++j) rB[j] = Bs[tid * PPT + j];
    }
    sync_lds();
#pragma unroll
    for (int ks = 0; ks < 2; ++ks) {
      int kb = ks * 64 + (lane >> 4) * 16;
      bf16x8 a[2];
#pragma unroll
      for (int mf = 0; mf < 2; ++mf) {
        int r = wm * 32 + mf * 16 + (lane & 15);
        a[mf] = *(const bf16x8*)(Ab + r * 128 + (kb ^ ((r & 7) << 4)));
      }
#pragma unroll
      for (int nf = 0; nf < NF; ++nf) {
        int d = wn * (OUTC / 2) + nf * 16 + (lane & 15);
        bf16x8 b = *(const bf16x8*)(Bb + d * 128 + (kb ^ ((d & 7) << 4)));
#pragma unroll
        for (int mf = 0; mf < 2; ++mf)
          acc[mf][nf] = __builtin_amdgcn_mfma_f32_16x16x32_bf16(
              a[mf], b, acc[mf][nf], 0, 0, 0);
      }
    }
    sync_lds();
  }

#pragma unroll
  for (int mf = 0; mf < 2; ++mf) {
    int rbase = n0 + wm * 32 + mf * 16 + (lane >> 4) * 4;
#pragma unroll
    for (int nf = 0; nf < NF; ++nf) {
      int c = wn * (OUTC / 2) + nf * 16 + (lane & 15);
#pragma unroll
      for (int r = 0; r < 4; ++r) {
        int row = rbase + r;
        if (row < M) out[row * OUTC + c] = acc[mf][nf][r];
      }
    }
  }

#pragma unroll
  for (int nf = 0; nf < NF; ++nf) {
    float s = 0.f, q = 0.f;
#pragma unroll
    for (int mf = 0; mf < 2; ++mf)
#pragma unroll
      for (int r = 0; r < 4; ++r) {
        float v = acc[mf][nf][r];
        s += v; q += v * v;
      }
    s += __shfl_xor(s, 16); s += __shfl_xor(s, 32);
    q += __shfl_xor(q, 16); q += __shfl_xor(q, 32);
    if (lane < 16) {
      int c = wn * (OUTC / 2) + nf * 16 + lane;
      atomicAdd(&stats[c], s);
      atomicAdd(&stats[OUTC + c], q);
    }
  }
}

// ---------------------------------------------------------------------------
// BN+ReLU on y2d channels 0..63 -> out1 (bf16)
// ---------------------------------------------------------------------------
__global__ __launch_bounds__(256) void k_bnrelu(
    const float* __restrict__ y2d, const float* __restrict__ stats,
    const float* __restrict__ gamma, const float* __restrict__ beta,
    unsigned short* __restrict__ out1) {
  int e = blockIdx.x * 256 + threadIdx.x;
  int i = e >> 6, c = e & 63;
  float2 ab = bn_ab(stats[c], stats[128 + c], 1.0f / CN3, gamma[c], beta[c]);
  out1[e] = f2bf(fmaxf(fmaf(ab.x, y2d[i * 128 + c], ab.y), 0.f));
}

// ---------------------------------------------------------------------------
// Final: relu(BN2(y3) + BNd(y2d[:,64:128]))
// ---------------------------------------------------------------------------
__global__ __launch_bounds__(256) void k_final(
    const float* __restrict__ y3, const float* __restrict__ y2d,
    const float* __restrict__ stats2, const float* __restrict__ stats1d,
    const float* __restrict__ g2, const float* __restrict__ b2,
    const float* __restrict__ gd, const float* __restrict__ bd,
    float* __restrict__ dout) {
  int e = blockIdx.x * 256 + threadIdx.x;
  int i = e >> 6, c = e & 63;
  float2 ab2 = bn_ab(stats2[c], stats2[64 + c], 1.0f / CN3, g2[c], b2[c]);
  float2 abd =
      bn_ab(stats1d[64 + c], stats1d[192 + c], 1.0f / CN3, gd[c], bd[c]);
  float o = fmaf(ab2.x, y3[e], ab2.y) + fmaf(abd.x, y2d[i * 128 + 64 + c], abd.y);
  dout[e] = fmaxf(o, 0.f);
}

// ---------------------------------------------------------------------------
extern "C" void kernel_launch(void* const* d_in, const int* in_sizes, int n_in,
                              void* d_out, int out_size, void* d_ws,
                              size_t ws_size, hipStream_t stream) {
  const float* x = (const float*)d_in[0];
  const int* neigh_stem = (const int*)d_in[1];
  const int* pool_child = (const int*)d_in[2];
  const int* neigh_ds = (const int*)d_in[3];
  const int* neigh_res = (const int*)d_in[4];
  const float* W_stem = (const float*)d_in[5];
  const float* g_stem = (const float*)d_in[6];
  const float* b_stem = (const float*)d_in[7];
  const float* W1 = (const float*)d_in[8];
  const float* g1 = (const float*)d_in[9];
  const float* b1 = (const float*)d_in[10];
  const float* W2 = (const float*)d_in[11];
  const float* g2 = (const float*)d_in[12];
  const float* b2 = (const float*)d_in[13];
  const float* Wd = (const float*)d_in[14];
  const float* gd = (const float*)d_in[15];
  const float* bd = (const float*)d_in[16];
  float* out = (float*)d_out;
  float* ws = (float*)d_ws;

  // Workspace layout (float units):
  unsigned short* y1bf = (unsigned short*)ws;              // N1*64 bf16 (9.6M f)
  float* y2d = ws;                                         // N3*128 f32 (reuse)
  unsigned short* out1bf = (unsigned short*)(ws + 3840000);// N3*64 bf16
  float* y3 = ws + 4800000;                                // N3*64 f32
  unsigned short* h2bf = (unsigned short*)(ws + 9600000);  // N2*64 bf16 (2.56M f)
  unsigned int* xbf = (unsigned int*)(ws + 12160000);      // N0*4 bf16 (2M f)
  unsigned short* Wst = (unsigned short*)(ws + 14160000);  // 8192 bf16
  unsigned short* Wdual = (unsigned short*)(ws + 14164096);// 27*128*64 bf16
  unsigned short* Wres = (unsigned short*)(ws + 14274688); // 27*64*64 bf16
  float* stats = ws + 14329984;                            // 512 f32
  float* stats_stem = stats;                               // [128]
  float* stats_1d = stats + 128;                           // [256]
  float* stats_2 = stats + 384;                            // [128]

  hipMemsetAsync(stats, 0, 512 * sizeof(float), stream);

  k_prep_x<<<(CN0 + 255) / 256, 256, 0, stream>>>(x, xbf);
  k_prep_stem<<<(8192 + 255) / 256, 256, 0, stream>>>(W_stem, Wst);
  k_prep_dual<<<(27 * 128 * 64 + 255) / 256, 256, 0, stream>>>(W1, Wd, Wdual);
  k_prep_res<<<(27 * 64 * 64 + 255) / 256, 256, 0, stream>>>(W2, Wres);

  // 4688 tiles of 64 nodes = 4 tiles x 1172 blocks
  k_stem_mfma<<<1172, 256, 0, stream>>>(
      (const unsigned short*)xbf, neigh_stem, Wst, y1bf, stats_stem);
  k_pool<<<CN2 / 8, 256, 0, stream>>>((const unsigned int*)y1bf, pool_child,
                                      stats_stem, g_stem, b_stem,
                                      (unsigned int*)h2bf);
  k_mconv<128><<<(CN3 + 63) / 64, 256, 0, stream>>>(h2bf, neigh_ds, Wdual,
                                                    y2d, stats_1d, CN3);
  k_bnrelu<<<CN3 * 64 / 256, 256, 0, stream>>>(y2d, stats_1d, g1, b1, out1bf);
  k_mconv<64><<<(CN3 + 63) / 64, 256, 0, stream>>>(out1bf, neigh_res, Wres,
                                                   y3, stats_2, CN3);
  k_final<<<CN3 * 64 / 256, 256, 0, stream>>>(y3, y2d, stats_2, stats_1d, g2,
                                              b2, gd, bd, out);
}